// Round 11
// baseline (237.537 us; speedup 1.0000x reference)
//
#include <hip/hip_runtime.h>
#include <math.h>

// LocalityAttention, fp16 single-pass MFMA.
// Algebra: softmax(Q K^T) = softmax(q G k^T + colterm), G = Wq^T Wk;
// KG = k G^T replaces the K projection; Q projection eliminated.
// Round 11: (1) k's fp16 convert fused into cterm (k read once);
// (2) KG and VT co-launched in one 384-block kernel (task by XCD parity,
// same 8-phase body) -> 1.5 blocks/CU instead of two 0.75-filled launches;
// (3) all small weight preps merged into the q/v convert launch.

typedef _Float16 f16x8 __attribute__((ext_vector_type(8)));
typedef _Float16 f16x4 __attribute__((ext_vector_type(4)));
typedef __attribute__((ext_vector_type(4))) float f32x4;

template<typename T>
__device__ __forceinline__ void async_copy16(T* lds, const T* g) {
    __builtin_amdgcn_global_load_lds(
        (const __attribute__((address_space(1))) unsigned int*)g,
        (__attribute__((address_space(3))) unsigned int*)lds, 16, 0, 0);
}

__device__ __forceinline__ void barrier_mem() {
    asm volatile("s_barrier" ::: "memory");
}

// ---------------- shared 8-phase 256x256 GEMM body --------------------------
// C[m,n] = sum_k A[m,k]*B[n,k]; K=k-extent; nt=K/64 even.
// bias_mode: 0 none, 1 bias[col], 2 bias[row].  EPI: 0 fp32, 1 fp16.
template<int EPI>
__device__ __forceinline__ void gemm256_body(
    const _Float16* __restrict__ A0, const _Float16* __restrict__ B0,
    const float* __restrict__ bias, void* __restrict__ C0,
    int K, int lda, int ldb, int ldc, long long cbase,
    int m0, int n0, int bias_mode, int tid, _Float16* smem)
{
    const int lane = tid & 63;
    const int wid  = tid >> 6;
    const int wm   = wid >> 2;
    const int wn   = wid & 3;
    const int fr   = lane & 15;
    const int fs   = lane >> 4;

    const int nt = K / 64;
    const int iters = nt / 2;

    auto stage_unit = [&](int dbuf, int isB, int unit, int tile) {
        if (tile >= nt) return;
        const int kt = tile * 64;
        const int lr = tid >> 3, s = tid & 7;
        const int grow = isB ? (unit * 64 + lr)
                             : (((lr >> 5) << 7) + unit * 32 + (lr & 31));
        const int gslot = s ^ (grow & 7);
        _Float16* dst = smem + dbuf * 32768 + isB * 16384 + grow * 64 + s * 8;
        const _Float16* src = (isB ? B0 : A0)
            + (size_t)((isB ? n0 : m0) + grow) * (size_t)(isB ? ldb : lda)
            + kt + gslot * 8;
        async_copy16(dst, src);
    };

    f32x4 acc[8][4] = {};
    f16x8 bf[4][2];

#define PHASE(BUF, Q, READB, STAGES, VMW) do {                                 \
    const _Float16* Ab = smem + (BUF) * 32768;                                 \
    const _Float16* Bb = Ab + 16384;                                           \
    f16x8 a0k0, a0k1, a1k0, a1k1;                                              \
    { const int r = wm * 128 + ((Q) * 2 + 0) * 16 + fr;                        \
      a0k0 = *(const f16x8*)&Ab[r * 64 + ((fs       ^ (r & 7)) * 8)];          \
      a0k1 = *(const f16x8*)&Ab[r * 64 + (((4 + fs) ^ (r & 7)) * 8)]; }        \
    { const int r = wm * 128 + ((Q) * 2 + 1) * 16 + fr;                        \
      a1k0 = *(const f16x8*)&Ab[r * 64 + ((fs       ^ (r & 7)) * 8)];          \
      a1k1 = *(const f16x8*)&Ab[r * 64 + (((4 + fs) ^ (r & 7)) * 8)]; }        \
    if (READB) {                                                               \
      _Pragma("unroll") for (int ni = 0; ni < 4; ++ni) {                       \
        const int r = wn * 64 + ni * 16 + fr;                                  \
        bf[ni][0] = *(const f16x8*)&Bb[r * 64 + ((fs       ^ (r & 7)) * 8)];   \
        bf[ni][1] = *(const f16x8*)&Bb[r * 64 + (((4 + fs) ^ (r & 7)) * 8)]; } \
    }                                                                          \
    STAGES;                                                                    \
    barrier_mem();                                                             \
    __builtin_amdgcn_s_setprio(1);                                             \
    _Pragma("unroll") for (int ni = 0; ni < 4; ++ni) {                         \
      acc[(Q)*2+0][ni] = __builtin_amdgcn_mfma_f32_16x16x32_f16(a0k0, bf[ni][0], acc[(Q)*2+0][ni], 0, 0, 0); \
      acc[(Q)*2+0][ni] = __builtin_amdgcn_mfma_f32_16x16x32_f16(a0k1, bf[ni][1], acc[(Q)*2+0][ni], 0, 0, 0); \
      acc[(Q)*2+1][ni] = __builtin_amdgcn_mfma_f32_16x16x32_f16(a1k0, bf[ni][0], acc[(Q)*2+1][ni], 0, 0, 0); \
      acc[(Q)*2+1][ni] = __builtin_amdgcn_mfma_f32_16x16x32_f16(a1k1, bf[ni][1], acc[(Q)*2+1][ni], 0, 0, 0); \
    }                                                                          \
    __builtin_amdgcn_s_setprio(0);                                             \
    VMW;                                                                       \
    barrier_mem();                                                             \
} while (0)

    stage_unit(0, 0, 0, 0); stage_unit(0, 0, 1, 0);
    stage_unit(0, 0, 2, 0); stage_unit(0, 0, 3, 0);
    stage_unit(0, 1, 0, 0); stage_unit(0, 1, 1, 0);
    stage_unit(0, 1, 2, 0); stage_unit(0, 1, 3, 0);
    stage_unit(1, 1, 0, 1); stage_unit(1, 1, 1, 1);
    stage_unit(1, 1, 2, 1); stage_unit(1, 1, 3, 1);
    stage_unit(1, 0, 0, 1); stage_unit(1, 0, 1, 1);
    asm volatile("s_waitcnt vmcnt(6)" ::: "memory");
    barrier_mem();

    for (int i = 0; i < iters; ++i) {
        const int T1 = 2 * i + 1, T2 = 2 * i + 2, T3 = 2 * i + 3;
        const bool last = (i + 1 == iters);
        PHASE(0, 0, 1, stage_unit(1, 0, 2, T1); stage_unit(1, 0, 3, T1), );
        PHASE(0, 1, 0, stage_unit(0, 1, 0, T2); stage_unit(0, 1, 1, T2), );
        PHASE(0, 2, 0, stage_unit(0, 1, 2, T2); stage_unit(0, 1, 3, T2), );
        PHASE(0, 3, 0, stage_unit(0, 0, 0, T2); stage_unit(0, 0, 1, T2),
              if (last) { asm volatile("s_waitcnt vmcnt(0)" ::: "memory"); }
              else      { asm volatile("s_waitcnt vmcnt(6)" ::: "memory"); });
        PHASE(1, 0, 1, stage_unit(0, 0, 2, T2); stage_unit(0, 0, 3, T2), );
        PHASE(1, 1, 0, stage_unit(1, 1, 0, T3); stage_unit(1, 1, 1, T3), );
        PHASE(1, 2, 0, stage_unit(1, 1, 2, T3); stage_unit(1, 1, 3, T3), );
        PHASE(1, 3, 0, stage_unit(1, 0, 0, T3); stage_unit(1, 0, 1, T3),
              asm volatile("s_waitcnt vmcnt(6)" ::: "memory"));
    }
#undef PHASE

    #pragma unroll
    for (int mi = 0; mi < 8; ++mi) {
        #pragma unroll
        for (int ni = 0; ni < 4; ++ni) {
            const int col = n0 + wn * 64 + ni * 16 + fr;
            #pragma unroll
            for (int r = 0; r < 4; ++r) {
                const int row = m0 + wm * 128 + mi * 16 + fs * 4 + r;
                float vv = acc[mi][ni][r];
                if (bias_mode == 1) vv += bias[col];
                if (bias_mode == 2) vv += bias[row];
                const size_t idx = (size_t)cbase + (size_t)row * ldc + col;
                if (EPI == 0) ((float*)C0)[idx] = vv;
                else          ((_Float16*)C0)[idx] = (_Float16)vv;
            }
        }
    }
}

// single-task 256x256 8-phase GEMM
template<int EPI, int BIAS>
__global__ __launch_bounds__(512, 2)
void mfma_gemm256(const _Float16* __restrict__ A, const _Float16* __restrict__ B,
                  const float* __restrict__ bias, void* __restrict__ C0,
                  int K, int lda, int ldb, int ldc,
                  long long sA, long long sB, long long sC)
{
    __shared__ _Float16 smem[65536];
    const int tid = threadIdx.x;
    const int gx = gridDim.x, gy = gridDim.y;
    const int nwg = gx * gy * gridDim.z;
    const int p = blockIdx.x + gx * (blockIdx.y + gy * blockIdx.z);
    const int cpx = nwg >> 3;
    const int l = (nwg & 7) ? p : (p & 7) * cpx + (p >> 3);
    const int bx = l % gx;
    const int by = (l / gx) % gy;
    const long long bz = l / (gx * gy);
    gemm256_body<EPI>(A + bz * sA, B + bz * sB, bias, C0,
                      K, lda, ldb, ldc, bz * sC,
                      by * 256, bx * 256, BIAS, tid, smem);
}

// dual-task co-launch: even XCDs run task0 (KG), odd run task1 (VT).
// 384 blocks; per task 192 blocks chunk-mapped to its 4 XCDs.
__global__ __launch_bounds__(512, 2)
void mfma_gemm256_dual(
    const _Float16* A_0, const _Float16* B_0, const float* bias_0, void* C_0,
    int lda_0, int ldb_0, int ldc_0, long long sA_0, long long sB_0,
    long long sC_0, int gx_0, int gy_0, int bm_0,
    const _Float16* A_1, const _Float16* B_1, const float* bias_1, void* C_1,
    int lda_1, int ldb_1, int ldc_1, long long sA_1, long long sB_1,
    long long sC_1, int gx_1, int gy_1, int bm_1, int K)
{
    __shared__ _Float16 smem[65536];
    const int tid = threadIdx.x;
    const int p = blockIdx.x;
    const int task = p & 1;
    const int l = ((p & 7) >> 1) * 48 + (p >> 3);   // [0,192) per task

    const int gx = task ? gx_1 : gx_0;
    const int gy = task ? gy_1 : gy_0;
    const int bx = l % gx;
    const int by = (l / gx) % gy;
    const long long bz = l / (gx * gy);

    const _Float16* A = (task ? A_1 : A_0) + bz * (task ? sA_1 : sA_0);
    const _Float16* B = (task ? B_1 : B_0) + bz * (task ? sB_1 : sB_0);
    gemm256_body<1>(A, B, task ? bias_1 : bias_0, task ? C_1 : C_0,
                    K, task ? lda_1 : lda_0, task ? ldb_1 : ldb_0,
                    task ? ldc_1 : ldc_0, bz * (task ? sC_1 : sC_0),
                    by * 256, bx * 256, task ? bm_1 : bm_0, tid, smem);
}

// ---------------- 128x128 2-phase GEMM (tiny G matmul) ----------------------
template<int EPI, int BIAS>
__global__ __launch_bounds__(256, 2)
void mfma_gemm(const _Float16* __restrict__ A, const _Float16* __restrict__ B,
               const float* __restrict__ bias,
               void* __restrict__ C0,
               int K, int lda, int ldb, int ldc,
               long long sA, long long sB, long long sC)
{
    __shared__ _Float16 sAh[128 * 32];
    __shared__ _Float16 sBh[128 * 32];

    const int tid = threadIdx.x;
    const int gx = gridDim.x, gy = gridDim.y;
    const int nwg = gx * gy * gridDim.z;
    const int p = blockIdx.x + gx * (blockIdx.y + gy * blockIdx.z);
    const int cpx = nwg >> 3;
    const int l = (nwg & 7) ? p : (p & 7) * cpx + (p >> 3);
    const int bx = l % gx;
    const int by = (l / gx) % gy;
    const long long bz = l / (gx * gy);

    const int m0 = by * 128;
    const int n0 = bx * 128;

    const _Float16* A0 = A + bz * sA;
    const _Float16* B0 = B + bz * sB;

    const int lrow  = tid >> 2;
    const int lslot = tid & 3;

    const int lane = tid & 63;
    const int wv   = tid >> 6;
    const int wm   = wv >> 1, wn = wv & 1;
    const int fr   = lane & 15;
    const int fs   = lane >> 4;
    const int sw   = fs ^ (fr & 3);
    const int abase = (wm * 64 + fr) * 32 + sw * 8;
    const int bbase = (wn * 64 + fr) * 32 + sw * 8;

    f32x4 acc[4][4] = {};

    for (int kt = 0; kt < K; kt += 32) {
        #pragma unroll
        for (int it = 0; it < 2; ++it) {
            const int row = lrow + it * 64;
            const int gsl = (lslot ^ (row & 3)) << 3;
            const size_t loff = (size_t)tid * 8 + (size_t)it * 2048;
            async_copy16(&sAh[loff], A0 + (size_t)(m0 + row) * lda + kt + gsl);
            async_copy16(&sBh[loff], B0 + (size_t)(n0 + row) * ldb + kt + gsl);
        }
        __syncthreads();

        f16x8 ah[4], bh[4];
        #pragma unroll
        for (int i = 0; i < 4; ++i) {
            ah[i] = *(const f16x8*)&sAh[abase + i * 512];
            bh[i] = *(const f16x8*)&sBh[bbase + i * 512];
        }
        #pragma unroll
        for (int mi = 0; mi < 4; ++mi)
            #pragma unroll
            for (int ni = 0; ni < 4; ++ni)
                acc[mi][ni] = __builtin_amdgcn_mfma_f32_16x16x32_f16(
                    ah[mi], bh[ni], acc[mi][ni], 0, 0, 0);
        __syncthreads();
    }

    const int er = fs * 4;
    #pragma unroll
    for (int mi = 0; mi < 4; ++mi) {
        #pragma unroll
        for (int ni = 0; ni < 4; ++ni) {
            const int col = n0 + wn * 64 + ni * 16 + fr;
            #pragma unroll
            for (int r = 0; r < 4; ++r) {
                const int row = m0 + wm * 64 + mi * 16 + er + r;
                float vv = acc[mi][ni][r];
                if (BIAS == 1) vv += bias[col];
                if (BIAS == 2) vv += bias[row];
                const size_t idx = (size_t)bz * sC + (size_t)row * ldc + col;
                if (EPI == 0) ((float*)C0)[idx] = vv;
                else          ((_Float16*)C0)[idx] = (_Float16)vv;
            }
        }
    }
}

// ---------------- fat prep: q,v converts + Wv convert + Wq/Wk transposes ----
// 1-D grid, range decode:
//  [0,3072)     q  -> qh   (16 elem/thread)
//  [3072,6144)  v  -> vh
//  [6144,6432)  Wv -> wvh  (8 elem/thread, 288 blocks)
//  [6432,6576)  Wq -> WqT  (144 transpose tiles)
//  [6576,6720)  Wk -> WkT
__global__ __launch_bounds__(256)
void fat_prep(const float* __restrict__ q, const float* __restrict__ v,
              const float* __restrict__ Wq, const float* __restrict__ Wk,
              const float* __restrict__ Wv,
              _Float16* __restrict__ qh, _Float16* __restrict__ vh,
              _Float16* __restrict__ WqT, _Float16* __restrict__ WkT,
              _Float16* __restrict__ wvh)
{
    __shared__ float t[64][65];
    const int p = blockIdx.x;
    const int tid = threadIdx.x;

    if (p < 6144) {
        const float* src = p < 3072 ? q : v;
        _Float16* dst    = p < 3072 ? qh : vh;
        const long long i = ((long long)(p < 3072 ? p : p - 3072) * 256 + tid) * 16;
        const float4 a = *(const float4*)&src[i];
        const float4 b = *(const float4*)&src[i + 4];
        const float4 c = *(const float4*)&src[i + 8];
        const float4 d = *(const float4*)&src[i + 12];
        f16x8 o0, o1;
        o0[0] = (_Float16)a.x; o0[1] = (_Float16)a.y;
        o0[2] = (_Float16)a.z; o0[3] = (_Float16)a.w;
        o0[4] = (_Float16)b.x; o0[5] = (_Float16)b.y;
        o0[6] = (_Float16)b.z; o0[7] = (_Float16)b.w;
        o1[0] = (_Float16)c.x; o1[1] = (_Float16)c.y;
        o1[2] = (_Float16)c.z; o1[3] = (_Float16)c.w;
        o1[4] = (_Float16)d.x; o1[5] = (_Float16)d.y;
        o1[6] = (_Float16)d.z; o1[7] = (_Float16)d.w;
        *(f16x8*)&dst[i] = o0;
        *(f16x8*)&dst[i + 8] = o1;
        return;
    }
    if (p < 6432) {
        const long long i = ((long long)(p - 6144) * 256 + tid) * 8;
        const float4 a = *(const float4*)&Wv[i];
        const float4 b = *(const float4*)&Wv[i + 4];
        f16x8 o;
        o[0] = (_Float16)a.x; o[1] = (_Float16)a.y;
        o[2] = (_Float16)a.z; o[3] = (_Float16)a.w;
        o[4] = (_Float16)b.x; o[5] = (_Float16)b.y;
        o[6] = (_Float16)b.z; o[7] = (_Float16)b.w;
        *(f16x8*)&wvh[i] = o;
        return;
    }
    // transpose tiles
    const int tno = p < 6576 ? p - 6432 : p - 6576;
    const float* src = p < 6576 ? Wq : Wk;
    _Float16* dst    = p < 6576 ? WqT : WkT;
    const int r0 = (tno / 12) * 64, c0 = (tno % 12) * 64;
    const int tx = tid & 63, ty = tid >> 6;
    #pragma unroll
    for (int r = 0; r < 16; ++r) {
        const int row = ty * 16 + r;
        t[row][tx] = src[(size_t)(r0 + row) * 768 + c0 + tx];
    }
    __syncthreads();
    #pragma unroll
    for (int r = 0; r < 16; ++r) {
        const int orow = ty * 16 + r;
        dst[(size_t)(c0 + orow) * 768 + r0 + tx] = (_Float16)t[tx][orow];
    }
}

// colvec[d] = sum_e WkT[d][e]*bq[e]
__global__ __launch_bounds__(256)
void colvec_kernel(const _Float16* __restrict__ WkT, const float* __restrict__ bq,
                   float* __restrict__ colvec, int n)
{
    const int wv = threadIdx.x >> 6, lane = threadIdx.x & 63;
    const int d = blockIdx.x * 4 + wv;
    float s = 0.f;
    for (int e = lane; e < n; e += 64)
        s += (float)WkT[(size_t)d * n + e] * bq[e];
    #pragma unroll
    for (int off = 32; off; off >>= 1) s += __shfl_down(s, off, 64);
    if (lane == 0) colvec[d] = s;
}

// cterm[row] = dot(k[row,:], colvec)  AND  kh[row,:] = (fp16)k[row,:].
// One wave per row; k read exactly once.
__global__ __launch_bounds__(256)
void cterm_cvt_kernel(const float* __restrict__ k, const float* __restrict__ colvec,
                      float* __restrict__ cterm, _Float16* __restrict__ kh)
{
    const int wv = threadIdx.x >> 6, lane = threadIdx.x & 63;
    const long long row = (long long)blockIdx.x * 4 + wv;
    const float* kp = k + row * 768;
    _Float16* op = kh + row * 768;
    float s = 0.f;
    #pragma unroll
    for (int i = 0; i < 3; ++i) {
        const float4 a = *(const float4*)&kp[lane * 4 + i * 256];
        const float4 c = *(const float4*)&colvec[lane * 4 + i * 256];
        s += a.x * c.x + a.y * c.y + a.z * c.z + a.w * c.w;
        f16x4 o;
        o[0] = (_Float16)a.x; o[1] = (_Float16)a.y;
        o[2] = (_Float16)a.z; o[3] = (_Float16)a.w;
        *(f16x4*)&op[lane * 4 + i * 256] = o;
    }
    #pragma unroll
    for (int off = 32; off; off >>= 1) s += __shfl_down(s, off, 64);
    if (lane == 0) cterm[row] = s;
}

// Row softmax with diag mask + per-column bias term; fp32 scores -> compact
// fp16 P (stride 1024). Block id XCD-swizzled to match the GEMM chunk maps.
__global__ __launch_bounds__(256)
void softmax_diag(const float* __restrict__ P, _Float16* __restrict__ Pout,
                  const float* __restrict__ tptr,
                  const float* __restrict__ cterm, int S)
{
    const int p = blockIdx.x;                       // 16384 = 8 * 2048
    const int row = (p & 7) * (16 * 1024 / 8) + (p >> 3);
    const int i   = row % S;
    const float* rp = P + (long long)row * S;
    const int tid = threadIdx.x;
    const float invt = 1.0f / tptr[0];

    const float4 v  = *(const float4*)&rp[tid * 4];
    const float4 ct = *(const float4*)&cterm[(long long)(row / S) * S + tid * 4];
    float vals[4] = {v.x + ct.x, v.y + ct.y, v.z + ct.z, v.w + ct.w};
    #pragma unroll
    for (int j = 0; j < 4; ++j) {
        vals[j] *= invt;
        if (tid * 4 + j == i) vals[j] = -INFINITY;
    }

    float mx = fmaxf(fmaxf(vals[0], vals[1]), fmaxf(vals[2], vals[3]));
    #pragma unroll
    for (int off = 32; off > 0; off >>= 1)
        mx = fmaxf(mx, __shfl_down(mx, off, 64));

    __shared__ float smax[4], ssum[4];
    const int wv = tid >> 6, ln = tid & 63;
    if (ln == 0) smax[wv] = mx;
    __syncthreads();
    mx = fmaxf(fmaxf(smax[0], smax[1]), fmaxf(smax[2], smax[3]));

    float e[4];
    float s = 0.f;
    #pragma unroll
    for (int j = 0; j < 4; ++j) { e[j] = expf(vals[j] - mx); s += e[j]; }
    #pragma unroll
    for (int off = 32; off > 0; off >>= 1)
        s += __shfl_down(s, off, 64);
    if (ln == 0) ssum[wv] = s;
    __syncthreads();
    s = ssum[0] + ssum[1] + ssum[2] + ssum[3];

    const float inv = 1.0f / s;
    f16x4 o;
    o[0] = (_Float16)(e[0] * inv);
    o[1] = (_Float16)(e[1] * inv);
    o[2] = (_Float16)(e[2] * inv);
    o[3] = (_Float16)(e[3] * inv);
    *(f16x4*)&Pout[(long long)row * S + tid * 4] = o;
}

extern "C" void kernel_launch(void* const* d_in, const int* in_sizes, int n_in,
                              void* d_out, int out_size, void* d_ws, size_t ws_size,
                              hipStream_t stream)
{
    const float* q    = (const float*)d_in[0];
    const float* k    = (const float*)d_in[1];
    const float* v    = (const float*)d_in[2];
    const float* Wq   = (const float*)d_in[3];
    const float* bq   = (const float*)d_in[4];
    const float* Wk   = (const float*)d_in[5];
    const float* bk   = (const float*)d_in[6];   // row-constant -> cancels in softmax
    const float* Wv   = (const float*)d_in[7];
    const float* bv   = (const float*)d_in[8];
    const float* temp = (const float*)d_in[9];
    (void)bk;

    const int S = 1024, D = 768;

    // ws layout (bytes), end 197,725,184 (< proven 202,574,848).
    // P (32 MB compact fp16) overlays qh+kh, both dead by softmax time.
    char* ws = (char*)d_ws;
    _Float16* qh  = (_Float16*)(ws + 0);          // 24 MB (dead after scores)
    _Float16* kh  = (_Float16*)(ws + 25165824);   // 24 MB (dead after KG)
    _Float16* Pc  = (_Float16*)(ws + 0);          // 32 MB compact P
    _Float16* vh  = (_Float16*)(ws + 50331648);   // 24 MB
    _Float16* VT  = (_Float16*)(ws + 75497472);   // 24 MB
    _Float16* KG  = (_Float16*)(ws + 100663296);  // 24 MB
    float*  scores = (float*)(ws + 125829120);    // 64 MiB
    _Float16* wvh = (_Float16*)(ws + 192937984);  // 1.125 MB
    _Float16* WqT = (_Float16*)(ws + 194117632);
    _Float16* WkT = (_Float16*)(ws + 195297280);
    _Float16* G   = (_Float16*)(ws + 196476928);
    float* colvec = (float*)(ws + 197656576);
    float* cterm  = (float*)(ws + 197659648);

    dim3 blk(256);
    dim3 blk512(512);

    // q/v converts + Wv convert + Wq/Wk transposes, one launch
    fat_prep<<<6720, blk, 0, stream>>>(q, v, Wq, Wk, Wv, qh, vh, WqT, WkT, wvh);

    // colvec = WkT*bq ; then cterm + k->fp16 in one pass over k
    colvec_kernel<<<192, blk, 0, stream>>>(WkT, bq, colvec, D);
    cterm_cvt_kernel<<<4096, blk, 0, stream>>>(k, colvec, cterm, kh);

    // G[d,d'] = sum_e Wq[e,d] Wk[e,d']  (tiny, 128^2 path)
    mfma_gemm<1, 0><<<dim3(6, 6, 1), blk, 0, stream>>>(
        WqT, WkT, nullptr, G,
        768, 768, 768, 768, 0, 0, 0);

    // co-launched:  task0 KG[j,d] = sum k[j,]G[d,]   (grid 3x64x1)
    //               task1 VT[b][e][s] = Wv v^T + bv  (grid 4x3x16)
    mfma_gemm256_dual<<<384, blk512, 0, stream>>>(
        kh, G, nullptr, KG, 768, 768, 768, 0, 0, 0, 3, 64, 0,
        wvh, vh, bv, VT, 768, 768, 1024, 0, (long long)S * D, (long long)D * S,
        4, 3, 2, 768);

    // scores[b] = q[b] (KG[b])^T  (M=N=1024, K=768)
    mfma_gemm256<0, 0><<<dim3(4, 4, 16), blk512, 0, stream>>>(
        qh, KG, nullptr, scores,
        768, 768, 768, 1024,
        (long long)S * D, (long long)S * D, (long long)S * S);

    // masked softmax (+ column bias term) -> compact fp16 P (stride 1024)
    softmax_diag<<<16 * S, blk, 0, stream>>>(scores, Pc, temp, cterm, S);

    // out[b] = P[b] VT[b]^T  (M=1024, N=768, K=1024; compact P, lda=1024)
    mfma_gemm256<0, 0><<<dim3(3, 4, 16), blk512, 0, stream>>>(
        Pc, VT, nullptr, d_out,
        1024, 1024, 1024, 768,
        (long long)S * S, (long long)D * S, (long long)S * D);
}

// Round 12
// 216.731 us; speedup vs baseline: 1.0960x; 1.0960x over previous
//
#include <hip/hip_runtime.h>
#include <math.h>

// LocalityAttention, fp16 single-pass MFMA.
// Algebra: softmax(Q K^T) = softmax(q G k^T + colterm), G = Wq^T Wk;
// KG = k G^T replaces the K projection; Q projection eliminated.
// Round 12: dual co-launch reverted (85.6 us vs ~60 sequential: 1 block/CU
// -> 2-round makespan + interference). q/v/k converts unified in one
// wave-per-row kernel (cterm_cvt's measured-fast pattern, ~5 TB/s).

typedef _Float16 f16x8 __attribute__((ext_vector_type(8)));
typedef _Float16 f16x4 __attribute__((ext_vector_type(4)));
typedef __attribute__((ext_vector_type(4))) float f32x4;

template<typename T>
__device__ __forceinline__ void async_copy16(T* lds, const T* g) {
    __builtin_amdgcn_global_load_lds(
        (const __attribute__((address_space(1))) unsigned int*)g,
        (__attribute__((address_space(3))) unsigned int*)lds, 16, 0, 0);
}

__device__ __forceinline__ void barrier_mem() {
    asm volatile("s_barrier" ::: "memory");
}

// ---------------- 256x256 8-phase GEMM: C[m,n] = sum_k A[m,k]*B[n,k] -----
// EPI: 0 fp32->C0; 1 fp16->C0.  BIAS: 0 none; 1 bias[col]; 2 bias[row].
template<int EPI, int BIAS>
__global__ __launch_bounds__(512, 2)
void mfma_gemm256(const _Float16* __restrict__ A, const _Float16* __restrict__ B,
                  const float* __restrict__ bias, void* __restrict__ C0,
                  int K, int lda, int ldb, int ldc,
                  long long sA, long long sB, long long sC)
{
    __shared__ _Float16 smem[65536];   // 128 KiB: [buf][op][256*64]

    const int tid = threadIdx.x;

    const int gx = gridDim.x, gy = gridDim.y;
    const int nwg = gx * gy * gridDim.z;
    const int p = blockIdx.x + gx * (blockIdx.y + gy * blockIdx.z);
    const int cpx = nwg >> 3;
    const int l = (nwg & 7) ? p : (p & 7) * cpx + (p >> 3);
    const int bx = l % gx;
    const int by = (l / gx) % gy;
    const long long bz = l / (gx * gy);
    const int m0 = by * 256, n0 = bx * 256;

    const _Float16* A0 = A + bz * sA;
    const _Float16* B0 = B + bz * sB;

    const int lane = tid & 63;
    const int wid  = tid >> 6;
    const int wm   = wid >> 2;        // 0..1: A half (128 rows)
    const int wn   = wid & 3;         // 0..3: B quarter (64 rows)
    const int fr   = lane & 15;
    const int fs   = lane >> 4;

    const int nt = K / 64;
    const int iters = nt / 2;

    auto stage_unit = [&](int dbuf, int isB, int unit, int tile) {
        if (tile >= nt) return;
        const int kt = tile * 64;
        const int lr = tid >> 3, s = tid & 7;
        const int grow = isB ? (unit * 64 + lr)
                             : (((lr >> 5) << 7) + unit * 32 + (lr & 31));
        const int gslot = s ^ (grow & 7);
        _Float16* dst = smem + dbuf * 32768 + isB * 16384 + grow * 64 + s * 8;
        const _Float16* src = (isB ? B0 : A0)
            + (size_t)((isB ? n0 : m0) + grow) * (size_t)(isB ? ldb : lda)
            + kt + gslot * 8;
        async_copy16(dst, src);
    };

    f32x4 acc[8][4] = {};
    f16x8 bf[4][2];

#define PHASE(BUF, Q, READB, STAGES, VMW) do {                                 \
    const _Float16* Ab = smem + (BUF) * 32768;                                 \
    const _Float16* Bb = Ab + 16384;                                           \
    f16x8 a0k0, a0k1, a1k0, a1k1;                                              \
    { const int r = wm * 128 + ((Q) * 2 + 0) * 16 + fr;                        \
      a0k0 = *(const f16x8*)&Ab[r * 64 + ((fs       ^ (r & 7)) * 8)];          \
      a0k1 = *(const f16x8*)&Ab[r * 64 + (((4 + fs) ^ (r & 7)) * 8)]; }        \
    { const int r = wm * 128 + ((Q) * 2 + 1) * 16 + fr;                        \
      a1k0 = *(const f16x8*)&Ab[r * 64 + ((fs       ^ (r & 7)) * 8)];          \
      a1k1 = *(const f16x8*)&Ab[r * 64 + (((4 + fs) ^ (r & 7)) * 8)]; }        \
    if (READB) {                                                               \
      _Pragma("unroll") for (int ni = 0; ni < 4; ++ni) {                       \
        const int r = wn * 64 + ni * 16 + fr;                                  \
        bf[ni][0] = *(const f16x8*)&Bb[r * 64 + ((fs       ^ (r & 7)) * 8)];   \
        bf[ni][1] = *(const f16x8*)&Bb[r * 64 + (((4 + fs) ^ (r & 7)) * 8)]; } \
    }                                                                          \
    STAGES;                                                                    \
    barrier_mem();                                                             \
    __builtin_amdgcn_s_setprio(1);                                             \
    _Pragma("unroll") for (int ni = 0; ni < 4; ++ni) {                         \
      acc[(Q)*2+0][ni] = __builtin_amdgcn_mfma_f32_16x16x32_f16(a0k0, bf[ni][0], acc[(Q)*2+0][ni], 0, 0, 0); \
      acc[(Q)*2+0][ni] = __builtin_amdgcn_mfma_f32_16x16x32_f16(a0k1, bf[ni][1], acc[(Q)*2+0][ni], 0, 0, 0); \
      acc[(Q)*2+1][ni] = __builtin_amdgcn_mfma_f32_16x16x32_f16(a1k0, bf[ni][0], acc[(Q)*2+1][ni], 0, 0, 0); \
      acc[(Q)*2+1][ni] = __builtin_amdgcn_mfma_f32_16x16x32_f16(a1k1, bf[ni][1], acc[(Q)*2+1][ni], 0, 0, 0); \
    }                                                                          \
    __builtin_amdgcn_s_setprio(0);                                             \
    VMW;                                                                       \
    barrier_mem();                                                             \
} while (0)

    stage_unit(0, 0, 0, 0); stage_unit(0, 0, 1, 0);
    stage_unit(0, 0, 2, 0); stage_unit(0, 0, 3, 0);
    stage_unit(0, 1, 0, 0); stage_unit(0, 1, 1, 0);
    stage_unit(0, 1, 2, 0); stage_unit(0, 1, 3, 0);
    stage_unit(1, 1, 0, 1); stage_unit(1, 1, 1, 1);
    stage_unit(1, 1, 2, 1); stage_unit(1, 1, 3, 1);
    stage_unit(1, 0, 0, 1); stage_unit(1, 0, 1, 1);
    asm volatile("s_waitcnt vmcnt(6)" ::: "memory");
    barrier_mem();

    for (int i = 0; i < iters; ++i) {
        const int T1 = 2 * i + 1, T2 = 2 * i + 2, T3 = 2 * i + 3;
        const bool last = (i + 1 == iters);
        PHASE(0, 0, 1, stage_unit(1, 0, 2, T1); stage_unit(1, 0, 3, T1), );
        PHASE(0, 1, 0, stage_unit(0, 1, 0, T2); stage_unit(0, 1, 1, T2), );
        PHASE(0, 2, 0, stage_unit(0, 1, 2, T2); stage_unit(0, 1, 3, T2), );
        PHASE(0, 3, 0, stage_unit(0, 0, 0, T2); stage_unit(0, 0, 1, T2),
              if (last) { asm volatile("s_waitcnt vmcnt(0)" ::: "memory"); }
              else      { asm volatile("s_waitcnt vmcnt(6)" ::: "memory"); });
        PHASE(1, 0, 1, stage_unit(0, 0, 2, T2); stage_unit(0, 0, 3, T2), );
        PHASE(1, 1, 0, stage_unit(1, 1, 0, T3); stage_unit(1, 1, 1, T3), );
        PHASE(1, 2, 0, stage_unit(1, 1, 2, T3); stage_unit(1, 1, 3, T3), );
        PHASE(1, 3, 0, stage_unit(1, 0, 0, T3); stage_unit(1, 0, 1, T3),
              asm volatile("s_waitcnt vmcnt(6)" ::: "memory"));
    }
#undef PHASE

    #pragma unroll
    for (int mi = 0; mi < 8; ++mi) {
        #pragma unroll
        for (int ni = 0; ni < 4; ++ni) {
            const int col = n0 + wn * 64 + ni * 16 + fr;
            #pragma unroll
            for (int r = 0; r < 4; ++r) {
                const int row = m0 + wm * 128 + mi * 16 + fs * 4 + r;
                float vv = acc[mi][ni][r];
                if (BIAS == 1) vv += bias[col];
                if (BIAS == 2) vv += bias[row];
                const size_t idx = (size_t)bz * sC + (size_t)row * ldc + col;
                if (EPI == 0) ((float*)C0)[idx] = vv;
                else          ((_Float16*)C0)[idx] = (_Float16)vv;
            }
        }
    }
}

// ---------------- 128x128 2-phase GEMM (tiny G matmul) ----------------------
template<int EPI, int BIAS>
__global__ __launch_bounds__(256, 2)
void mfma_gemm(const _Float16* __restrict__ A, const _Float16* __restrict__ B,
               const float* __restrict__ bias,
               void* __restrict__ C0,
               int K, int lda, int ldb, int ldc,
               long long sA, long long sB, long long sC)
{
    __shared__ _Float16 sAh[128 * 32];
    __shared__ _Float16 sBh[128 * 32];

    const int tid = threadIdx.x;
    const int gx = gridDim.x, gy = gridDim.y;
    const int nwg = gx * gy * gridDim.z;
    const int p = blockIdx.x + gx * (blockIdx.y + gy * blockIdx.z);
    const int cpx = nwg >> 3;
    const int l = (nwg & 7) ? p : (p & 7) * cpx + (p >> 3);
    const int bx = l % gx;
    const int by = (l / gx) % gy;
    const long long bz = l / (gx * gy);

    const int m0 = by * 128;
    const int n0 = bx * 128;

    const _Float16* A0 = A + bz * sA;
    const _Float16* B0 = B + bz * sB;

    const int lrow  = tid >> 2;
    const int lslot = tid & 3;

    const int lane = tid & 63;
    const int wv   = tid >> 6;
    const int wm   = wv >> 1, wn = wv & 1;
    const int fr   = lane & 15;
    const int fs   = lane >> 4;
    const int sw   = fs ^ (fr & 3);
    const int abase = (wm * 64 + fr) * 32 + sw * 8;
    const int bbase = (wn * 64 + fr) * 32 + sw * 8;

    f32x4 acc[4][4] = {};

    for (int kt = 0; kt < K; kt += 32) {
        #pragma unroll
        for (int it = 0; it < 2; ++it) {
            const int row = lrow + it * 64;
            const int gsl = (lslot ^ (row & 3)) << 3;
            const size_t loff = (size_t)tid * 8 + (size_t)it * 2048;
            async_copy16(&sAh[loff], A0 + (size_t)(m0 + row) * lda + kt + gsl);
            async_copy16(&sBh[loff], B0 + (size_t)(n0 + row) * ldb + kt + gsl);
        }
        __syncthreads();

        f16x8 ah[4], bh[4];
        #pragma unroll
        for (int i = 0; i < 4; ++i) {
            ah[i] = *(const f16x8*)&sAh[abase + i * 512];
            bh[i] = *(const f16x8*)&sBh[bbase + i * 512];
        }
        #pragma unroll
        for (int mi = 0; mi < 4; ++mi)
            #pragma unroll
            for (int ni = 0; ni < 4; ++ni)
                acc[mi][ni] = __builtin_amdgcn_mfma_f32_16x16x32_f16(
                    ah[mi], bh[ni], acc[mi][ni], 0, 0, 0);
        __syncthreads();
    }

    const int er = fs * 4;
    #pragma unroll
    for (int mi = 0; mi < 4; ++mi) {
        #pragma unroll
        for (int ni = 0; ni < 4; ++ni) {
            const int col = n0 + wn * 64 + ni * 16 + fr;
            #pragma unroll
            for (int r = 0; r < 4; ++r) {
                const int row = m0 + wm * 64 + mi * 16 + er + r;
                float vv = acc[mi][ni][r];
                if (BIAS == 1) vv += bias[col];
                if (BIAS == 2) vv += bias[row];
                const size_t idx = (size_t)bz * sC + (size_t)row * ldc + col;
                if (EPI == 0) ((float*)C0)[idx] = vv;
                else          ((_Float16*)C0)[idx] = (_Float16)vv;
            }
        }
    }
}

// ---------------- weights prep: Wv convert + Wq/Wk transposes ---------------
//  [0,288)    Wv -> wvh  (8 elem/thread)
//  [288,432)  Wq -> WqT  (144 transpose tiles)
//  [432,576)  Wk -> WkT
__global__ __launch_bounds__(256)
void weights_prep(const float* __restrict__ Wq, const float* __restrict__ Wk,
                  const float* __restrict__ Wv,
                  _Float16* __restrict__ WqT, _Float16* __restrict__ WkT,
                  _Float16* __restrict__ wvh)
{
    __shared__ float t[64][65];
    const int p = blockIdx.x;
    const int tid = threadIdx.x;

    if (p < 288) {
        const long long i = ((long long)p * 256 + tid) * 8;
        const float4 a = *(const float4*)&Wv[i];
        const float4 b = *(const float4*)&Wv[i + 4];
        f16x8 o;
        o[0] = (_Float16)a.x; o[1] = (_Float16)a.y;
        o[2] = (_Float16)a.z; o[3] = (_Float16)a.w;
        o[4] = (_Float16)b.x; o[5] = (_Float16)b.y;
        o[6] = (_Float16)b.z; o[7] = (_Float16)b.w;
        *(f16x8*)&wvh[i] = o;
        return;
    }
    const int tno = p < 432 ? p - 288 : p - 432;
    const float* src = p < 432 ? Wq : Wk;
    _Float16* dst    = p < 432 ? WqT : WkT;
    const int r0 = (tno / 12) * 64, c0 = (tno % 12) * 64;
    const int tx = tid & 63, ty = tid >> 6;
    #pragma unroll
    for (int r = 0; r < 16; ++r) {
        const int row = ty * 16 + r;
        t[row][tx] = src[(size_t)(r0 + row) * 768 + c0 + tx];
    }
    __syncthreads();
    #pragma unroll
    for (int r = 0; r < 16; ++r) {
        const int orow = ty * 16 + r;
        dst[(size_t)(c0 + orow) * 768 + r0 + tx] = (_Float16)t[tx][orow];
    }
}

// colvec[d] = sum_e WkT[d][e]*bq[e]
__global__ __launch_bounds__(256)
void colvec_kernel(const _Float16* __restrict__ WkT, const float* __restrict__ bq,
                   float* __restrict__ colvec, int n)
{
    const int wv = threadIdx.x >> 6, lane = threadIdx.x & 63;
    const int d = blockIdx.x * 4 + wv;
    float s = 0.f;
    for (int e = lane; e < n; e += 64)
        s += (float)WkT[(size_t)d * n + e] * bq[e];
    #pragma unroll
    for (int off = 32; off; off >>= 1) s += __shfl_down(s, off, 64);
    if (lane == 0) colvec[d] = s;
}

// Unified row-pattern convert (one wave per 768-elem row):
//  [0,4096)      k -> kh + cterm[row] = dot(k[row], colvec)
//  [4096,8192)   q -> qh
//  [8192,12288)  v -> vh
__global__ __launch_bounds__(256)
void row_prep(const float* __restrict__ k, const float* __restrict__ q,
              const float* __restrict__ v, const float* __restrict__ colvec,
              float* __restrict__ cterm, _Float16* __restrict__ kh,
              _Float16* __restrict__ qh, _Float16* __restrict__ vh)
{
    const int p = blockIdx.x;
    const int wv = threadIdx.x >> 6, lane = threadIdx.x & 63;

    if (p < 4096) {
        const long long row = (long long)p * 4 + wv;
        const float* kp = k + row * 768;
        _Float16* op = kh + row * 768;
        float s = 0.f;
        #pragma unroll
        for (int i = 0; i < 3; ++i) {
            const float4 a = *(const float4*)&kp[lane * 4 + i * 256];
            const float4 c = *(const float4*)&colvec[lane * 4 + i * 256];
            s += a.x * c.x + a.y * c.y + a.z * c.z + a.w * c.w;
            f16x4 o;
            o[0] = (_Float16)a.x; o[1] = (_Float16)a.y;
            o[2] = (_Float16)a.z; o[3] = (_Float16)a.w;
            *(f16x4*)&op[lane * 4 + i * 256] = o;
        }
        #pragma unroll
        for (int off = 32; off; off >>= 1) s += __shfl_down(s, off, 64);
        if (lane == 0) cterm[row] = s;
        return;
    }
    const int pp = p & 4095;
    const float* src = p < 8192 ? q : v;
    _Float16* dst    = p < 8192 ? qh : vh;
    const long long row = (long long)pp * 4 + wv;
    const float* sp = src + row * 768;
    _Float16* op = dst + row * 768;
    #pragma unroll
    for (int i = 0; i < 3; ++i) {
        const float4 a = *(const float4*)&sp[lane * 4 + i * 256];
        f16x4 o;
        o[0] = (_Float16)a.x; o[1] = (_Float16)a.y;
        o[2] = (_Float16)a.z; o[3] = (_Float16)a.w;
        *(f16x4*)&op[lane * 4 + i * 256] = o;
    }
}

// Row softmax with diag mask + per-column bias term; fp32 scores -> compact
// fp16 P (stride 1024). Block id XCD-swizzled to match the GEMM chunk maps.
__global__ __launch_bounds__(256)
void softmax_diag(const float* __restrict__ P, _Float16* __restrict__ Pout,
                  const float* __restrict__ tptr,
                  const float* __restrict__ cterm, int S)
{
    const int p = blockIdx.x;                       // 16384 = 8 * 2048
    const int row = (p & 7) * (16 * 1024 / 8) + (p >> 3);
    const int i   = row % S;
    const float* rp = P + (long long)row * S;
    const int tid = threadIdx.x;
    const float invt = 1.0f / tptr[0];

    const float4 v  = *(const float4*)&rp[tid * 4];
    const float4 ct = *(const float4*)&cterm[(long long)(row / S) * S + tid * 4];
    float vals[4] = {v.x + ct.x, v.y + ct.y, v.z + ct.z, v.w + ct.w};
    #pragma unroll
    for (int j = 0; j < 4; ++j) {
        vals[j] *= invt;
        if (tid * 4 + j == i) vals[j] = -INFINITY;
    }

    float mx = fmaxf(fmaxf(vals[0], vals[1]), fmaxf(vals[2], vals[3]));
    #pragma unroll
    for (int off = 32; off > 0; off >>= 1)
        mx = fmaxf(mx, __shfl_down(mx, off, 64));

    __shared__ float smax[4], ssum[4];
    const int wv = tid >> 6, ln = tid & 63;
    if (ln == 0) smax[wv] = mx;
    __syncthreads();
    mx = fmaxf(fmaxf(smax[0], smax[1]), fmaxf(smax[2], smax[3]));

    float e[4];
    float s = 0.f;
    #pragma unroll
    for (int j = 0; j < 4; ++j) { e[j] = expf(vals[j] - mx); s += e[j]; }
    #pragma unroll
    for (int off = 32; off > 0; off >>= 1)
        s += __shfl_down(s, off, 64);
    if (ln == 0) ssum[wv] = s;
    __syncthreads();
    s = ssum[0] + ssum[1] + ssum[2] + ssum[3];

    const float inv = 1.0f / s;
    f16x4 o;
    o[0] = (_Float16)(e[0] * inv);
    o[1] = (_Float16)(e[1] * inv);
    o[2] = (_Float16)(e[2] * inv);
    o[3] = (_Float16)(e[3] * inv);
    *(f16x4*)&Pout[(long long)row * S + tid * 4] = o;
}

extern "C" void kernel_launch(void* const* d_in, const int* in_sizes, int n_in,
                              void* d_out, int out_size, void* d_ws, size_t ws_size,
                              hipStream_t stream)
{
    const float* q    = (const float*)d_in[0];
    const float* k    = (const float*)d_in[1];
    const float* v    = (const float*)d_in[2];
    const float* Wq   = (const float*)d_in[3];
    const float* bq   = (const float*)d_in[4];
    const float* Wk   = (const float*)d_in[5];
    const float* bk   = (const float*)d_in[6];   // row-constant -> cancels in softmax
    const float* Wv   = (const float*)d_in[7];
    const float* bv   = (const float*)d_in[8];
    const float* temp = (const float*)d_in[9];
    (void)bk;

    const int S = 1024, D = 768;

    // ws layout (bytes), end 197,725,184 (< proven 202,574,848).
    // P (32 MB compact fp16) overlays qh+kh, both dead by softmax time.
    char* ws = (char*)d_ws;
    _Float16* qh  = (_Float16*)(ws + 0);          // 24 MB (dead after scores)
    _Float16* kh  = (_Float16*)(ws + 25165824);   // 24 MB (dead after KG)
    _Float16* Pc  = (_Float16*)(ws + 0);          // 32 MB compact P
    _Float16* vh  = (_Float16*)(ws + 50331648);   // 24 MB
    _Float16* VT  = (_Float16*)(ws + 75497472);   // 24 MB
    _Float16* KG  = (_Float16*)(ws + 100663296);  // 24 MB
    float*  scores = (float*)(ws + 125829120);    // 64 MiB
    _Float16* wvh = (_Float16*)(ws + 192937984);  // 1.125 MB
    _Float16* WqT = (_Float16*)(ws + 194117632);
    _Float16* WkT = (_Float16*)(ws + 195297280);
    _Float16* G   = (_Float16*)(ws + 196476928);
    float* colvec = (float*)(ws + 197656576);
    float* cterm  = (float*)(ws + 197659648);

    dim3 blk(256);
    dim3 blk512(512);

    // weight preps, then colvec (needs WkT), then unified k/q/v row convert
    weights_prep<<<576, blk, 0, stream>>>(Wq, Wk, Wv, WqT, WkT, wvh);
    colvec_kernel<<<192, blk, 0, stream>>>(WkT, bq, colvec, D);
    row_prep<<<12288, blk, 0, stream>>>(k, q, v, colvec, cterm, kh, qh, vh);

    // G[d,d'] = sum_e Wq[e,d] Wk[e,d']  (tiny, 128^2 path)
    mfma_gemm<1, 0><<<dim3(6, 6, 1), blk, 0, stream>>>(
        WqT, WkT, nullptr, G,
        768, 768, 768, 768, 0, 0, 0);

    // KG[j,d] = sum_d' k[j,d'] G[d,d']  (M=16384 flat, N=768, K=768)
    mfma_gemm256<1, 0><<<dim3(3, 64, 1), blk512, 0, stream>>>(
        kh, G, nullptr, KG,
        768, 768, 768, 768, 0, 0, 0);

    // VT[b][e][s] = sum_d Wv[e,d] v[b,s,d] + bv[e]  (M=768, N=1024, K=768)
    mfma_gemm256<1, 2><<<dim3(4, 3, 16), blk512, 0, stream>>>(
        wvh, vh, bv, VT,
        768, 768, 768, 1024, 0, (long long)S * D, (long long)D * S);

    // scores[b] = q[b] (KG[b])^T  (M=N=1024, K=768)
    mfma_gemm256<0, 0><<<dim3(4, 4, 16), blk512, 0, stream>>>(
        qh, KG, nullptr, scores,
        768, 768, 768, 1024,
        (long long)S * D, (long long)S * D, (long long)S * S);

    // masked softmax (+ column bias term) -> compact fp16 P (stride 1024)
    softmax_diag<<<16 * S, blk, 0, stream>>>(scores, Pc, temp, cterm, S);

    // out[b] = P[b] VT[b]^T  (M=1024, N=768, K=1024; compact P, lda=1024)
    mfma_gemm256<0, 0><<<dim3(3, 4, 16), blk512, 0, stream>>>(
        Pc, VT, nullptr, d_out,
        1024, 1024, 1024, 768,
        (long long)S * S, (long long)D * S, (long long)S * D);
}

// Round 14
// 206.028 us; speedup vs baseline: 1.1529x; 1.0519x over previous
//
#include <hip/hip_runtime.h>
#include <math.h>

// LocalityAttention, fp16 single-pass MFMA.
// Algebra: softmax(Q K^T) = softmax(q G k^T + colterm), G = Wq^T Wk;
// KG = k G^T replaces the K projection; Q projection eliminated.
// Round 14 (= round 13 + compile fix): nontemporal loads must use native
// ext_vector types, not HIP_vector_type. (1) cterm + 1/temp + diag-mask folded
// into the scores GEMM epilogue; (2) pure wave-per-row barrier-free softmax;
// (3) nontemporal loads on single-use fp32 input streams in row_prep.

typedef _Float16 f16x8 __attribute__((ext_vector_type(8)));
typedef _Float16 f16x4 __attribute__((ext_vector_type(4)));
typedef float f32x4 __attribute__((ext_vector_type(4)));

template<typename T>
__device__ __forceinline__ void async_copy16(T* lds, const T* g) {
    __builtin_amdgcn_global_load_lds(
        (const __attribute__((address_space(1))) unsigned int*)g,
        (__attribute__((address_space(3))) unsigned int*)lds, 16, 0, 0);
}

__device__ __forceinline__ void barrier_mem() {
    asm volatile("s_barrier" ::: "memory");
}

// ---------------- 256x256 8-phase GEMM: C[m,n] = sum_k A[m,k]*B[n,k] -----
// EPI: 0 fp32->C0; 1 fp16->C0; 2 fp32 scores: ((acc+cterm[bz*1024+col])/temp,
//      diag -> -inf).  BIAS: 0 none; 1 bias[col]; 2 bias[row].
template<int EPI, int BIAS>
__global__ __launch_bounds__(512, 2)
void mfma_gemm256(const _Float16* __restrict__ A, const _Float16* __restrict__ B,
                  const float* __restrict__ bias, void* __restrict__ C0,
                  int K, int lda, int ldb, int ldc,
                  long long sA, long long sB, long long sC,
                  const float* __restrict__ tptr, const float* __restrict__ cterm)
{
    __shared__ _Float16 smem[65536];   // 128 KiB: [buf][op][256*64]

    const int tid = threadIdx.x;

    const int gx = gridDim.x, gy = gridDim.y;
    const int nwg = gx * gy * gridDim.z;
    const int p = blockIdx.x + gx * (blockIdx.y + gy * blockIdx.z);
    const int cpx = nwg >> 3;
    const int l = (nwg & 7) ? p : (p & 7) * cpx + (p >> 3);
    const int bx = l % gx;
    const int by = (l / gx) % gy;
    const long long bz = l / (gx * gy);
    const int m0 = by * 256, n0 = bx * 256;

    const _Float16* A0 = A + bz * sA;
    const _Float16* B0 = B + bz * sB;

    const int lane = tid & 63;
    const int wid  = tid >> 6;
    const int wm   = wid >> 2;        // 0..1: A half (128 rows)
    const int wn   = wid & 3;         // 0..3: B quarter (64 rows)
    const int fr   = lane & 15;
    const int fs   = lane >> 4;

    const int nt = K / 64;
    const int iters = nt / 2;

    auto stage_unit = [&](int dbuf, int isB, int unit, int tile) {
        if (tile >= nt) return;
        const int kt = tile * 64;
        const int lr = tid >> 3, s = tid & 7;
        const int grow = isB ? (unit * 64 + lr)
                             : (((lr >> 5) << 7) + unit * 32 + (lr & 31));
        const int gslot = s ^ (grow & 7);
        _Float16* dst = smem + dbuf * 32768 + isB * 16384 + grow * 64 + s * 8;
        const _Float16* src = (isB ? B0 : A0)
            + (size_t)((isB ? n0 : m0) + grow) * (size_t)(isB ? ldb : lda)
            + kt + gslot * 8;
        async_copy16(dst, src);
    };

    f32x4 acc[8][4] = {};
    f16x8 bf[4][2];

#define PHASE(BUF, Q, READB, STAGES, VMW) do {                                 \
    const _Float16* Ab = smem + (BUF) * 32768;                                 \
    const _Float16* Bb = Ab + 16384;                                           \
    f16x8 a0k0, a0k1, a1k0, a1k1;                                              \
    { const int r = wm * 128 + ((Q) * 2 + 0) * 16 + fr;                        \
      a0k0 = *(const f16x8*)&Ab[r * 64 + ((fs       ^ (r & 7)) * 8)];          \
      a0k1 = *(const f16x8*)&Ab[r * 64 + (((4 + fs) ^ (r & 7)) * 8)]; }        \
    { const int r = wm * 128 + ((Q) * 2 + 1) * 16 + fr;                        \
      a1k0 = *(const f16x8*)&Ab[r * 64 + ((fs       ^ (r & 7)) * 8)];          \
      a1k1 = *(const f16x8*)&Ab[r * 64 + (((4 + fs) ^ (r & 7)) * 8)]; }        \
    if (READB) {                                                               \
      _Pragma("unroll") for (int ni = 0; ni < 4; ++ni) {                       \
        const int r = wn * 64 + ni * 16 + fr;                                  \
        bf[ni][0] = *(const f16x8*)&Bb[r * 64 + ((fs       ^ (r & 7)) * 8)];   \
        bf[ni][1] = *(const f16x8*)&Bb[r * 64 + (((4 + fs) ^ (r & 7)) * 8)]; } \
    }                                                                          \
    STAGES;                                                                    \
    barrier_mem();                                                             \
    __builtin_amdgcn_s_setprio(1);                                             \
    _Pragma("unroll") for (int ni = 0; ni < 4; ++ni) {                         \
      acc[(Q)*2+0][ni] = __builtin_amdgcn_mfma_f32_16x16x32_f16(a0k0, bf[ni][0], acc[(Q)*2+0][ni], 0, 0, 0); \
      acc[(Q)*2+0][ni] = __builtin_amdgcn_mfma_f32_16x16x32_f16(a0k1, bf[ni][1], acc[(Q)*2+0][ni], 0, 0, 0); \
      acc[(Q)*2+1][ni] = __builtin_amdgcn_mfma_f32_16x16x32_f16(a1k0, bf[ni][0], acc[(Q)*2+1][ni], 0, 0, 0); \
      acc[(Q)*2+1][ni] = __builtin_amdgcn_mfma_f32_16x16x32_f16(a1k1, bf[ni][1], acc[(Q)*2+1][ni], 0, 0, 0); \
    }                                                                          \
    __builtin_amdgcn_s_setprio(0);                                             \
    VMW;                                                                       \
    barrier_mem();                                                             \
} while (0)

    stage_unit(0, 0, 0, 0); stage_unit(0, 0, 1, 0);
    stage_unit(0, 0, 2, 0); stage_unit(0, 0, 3, 0);
    stage_unit(0, 1, 0, 0); stage_unit(0, 1, 1, 0);
    stage_unit(0, 1, 2, 0); stage_unit(0, 1, 3, 0);
    stage_unit(1, 1, 0, 1); stage_unit(1, 1, 1, 1);
    stage_unit(1, 1, 2, 1); stage_unit(1, 1, 3, 1);
    stage_unit(1, 0, 0, 1); stage_unit(1, 0, 1, 1);
    asm volatile("s_waitcnt vmcnt(6)" ::: "memory");
    barrier_mem();

    for (int i = 0; i < iters; ++i) {
        const int T1 = 2 * i + 1, T2 = 2 * i + 2, T3 = 2 * i + 3;
        const bool last = (i + 1 == iters);
        PHASE(0, 0, 1, stage_unit(1, 0, 2, T1); stage_unit(1, 0, 3, T1), );
        PHASE(0, 1, 0, stage_unit(0, 1, 0, T2); stage_unit(0, 1, 1, T2), );
        PHASE(0, 2, 0, stage_unit(0, 1, 2, T2); stage_unit(0, 1, 3, T2), );
        PHASE(0, 3, 0, stage_unit(0, 0, 0, T2); stage_unit(0, 0, 1, T2),
              if (last) { asm volatile("s_waitcnt vmcnt(0)" ::: "memory"); }
              else      { asm volatile("s_waitcnt vmcnt(6)" ::: "memory"); });
        PHASE(1, 0, 1, stage_unit(0, 0, 2, T2); stage_unit(0, 0, 3, T2), );
        PHASE(1, 1, 0, stage_unit(1, 1, 0, T3); stage_unit(1, 1, 1, T3), );
        PHASE(1, 2, 0, stage_unit(1, 1, 2, T3); stage_unit(1, 1, 3, T3), );
        PHASE(1, 3, 0, stage_unit(1, 0, 0, T3); stage_unit(1, 0, 1, T3),
              asm volatile("s_waitcnt vmcnt(6)" ::: "memory"));
    }
#undef PHASE

    // epilogue constants for scores mode
    float invt = 0.f, ct[4];
    if (EPI == 2) {
        invt = 1.0f / tptr[0];
        #pragma unroll
        for (int ni = 0; ni < 4; ++ni)
            ct[ni] = cterm[bz * 1024 + n0 + wn * 64 + ni * 16 + fr];
    }

    #pragma unroll
    for (int mi = 0; mi < 8; ++mi) {
        #pragma unroll
        for (int ni = 0; ni < 4; ++ni) {
            const int col = n0 + wn * 64 + ni * 16 + fr;
            #pragma unroll
            for (int r = 0; r < 4; ++r) {
                const int row = m0 + wm * 128 + mi * 16 + fs * 4 + r;
                float vv = acc[mi][ni][r];
                if (BIAS == 1) vv += bias[col];
                if (BIAS == 2) vv += bias[row];
                const size_t idx = (size_t)bz * sC + (size_t)row * ldc + col;
                if (EPI == 0) {
                    ((float*)C0)[idx] = vv;
                } else if (EPI == 2) {
                    vv = (vv + ct[ni]) * invt;
                    if (row == col) vv = -INFINITY;
                    ((float*)C0)[idx] = vv;
                } else {
                    ((_Float16*)C0)[idx] = (_Float16)vv;
                }
            }
        }
    }
}

// ---------------- 128x128 2-phase GEMM (tiny G matmul) ----------------------
template<int EPI, int BIAS>
__global__ __launch_bounds__(256, 2)
void mfma_gemm(const _Float16* __restrict__ A, const _Float16* __restrict__ B,
               const float* __restrict__ bias,
               void* __restrict__ C0,
               int K, int lda, int ldb, int ldc,
               long long sA, long long sB, long long sC)
{
    __shared__ _Float16 sAh[128 * 32];
    __shared__ _Float16 sBh[128 * 32];

    const int tid = threadIdx.x;
    const int gx = gridDim.x, gy = gridDim.y;
    const int nwg = gx * gy * gridDim.z;
    const int p = blockIdx.x + gx * (blockIdx.y + gy * blockIdx.z);
    const int cpx = nwg >> 3;
    const int l = (nwg & 7) ? p : (p & 7) * cpx + (p >> 3);
    const int bx = l % gx;
    const int by = (l / gx) % gy;
    const long long bz = l / (gx * gy);

    const int m0 = by * 128;
    const int n0 = bx * 128;

    const _Float16* A0 = A + bz * sA;
    const _Float16* B0 = B + bz * sB;

    const int lrow  = tid >> 2;
    const int lslot = tid & 3;

    const int lane = tid & 63;
    const int wv   = tid >> 6;
    const int wm   = wv >> 1, wn = wv & 1;
    const int fr   = lane & 15;
    const int fs   = lane >> 4;
    const int sw   = fs ^ (fr & 3);
    const int abase = (wm * 64 + fr) * 32 + sw * 8;
    const int bbase = (wn * 64 + fr) * 32 + sw * 8;

    f32x4 acc[4][4] = {};

    for (int kt = 0; kt < K; kt += 32) {
        #pragma unroll
        for (int it = 0; it < 2; ++it) {
            const int row = lrow + it * 64;
            const int gsl = (lslot ^ (row & 3)) << 3;
            const size_t loff = (size_t)tid * 8 + (size_t)it * 2048;
            async_copy16(&sAh[loff], A0 + (size_t)(m0 + row) * lda + kt + gsl);
            async_copy16(&sBh[loff], B0 + (size_t)(n0 + row) * ldb + kt + gsl);
        }
        __syncthreads();

        f16x8 ah[4], bh[4];
        #pragma unroll
        for (int i = 0; i < 4; ++i) {
            ah[i] = *(const f16x8*)&sAh[abase + i * 512];
            bh[i] = *(const f16x8*)&sBh[bbase + i * 512];
        }
        #pragma unroll
        for (int mi = 0; mi < 4; ++mi)
            #pragma unroll
            for (int ni = 0; ni < 4; ++ni)
                acc[mi][ni] = __builtin_amdgcn_mfma_f32_16x16x32_f16(
                    ah[mi], bh[ni], acc[mi][ni], 0, 0, 0);
        __syncthreads();
    }

    const int er = fs * 4;
    #pragma unroll
    for (int mi = 0; mi < 4; ++mi) {
        #pragma unroll
        for (int ni = 0; ni < 4; ++ni) {
            const int col = n0 + wn * 64 + ni * 16 + fr;
            #pragma unroll
            for (int r = 0; r < 4; ++r) {
                const int row = m0 + wm * 64 + mi * 16 + er + r;
                float vv = acc[mi][ni][r];
                if (BIAS == 1) vv += bias[col];
                if (BIAS == 2) vv += bias[row];
                const size_t idx = (size_t)bz * sC + (size_t)row * ldc + col;
                if (EPI == 0) ((float*)C0)[idx] = vv;
                else          ((_Float16*)C0)[idx] = (_Float16)vv;
            }
        }
    }
}

// ---------------- weights prep: Wv convert + Wq/Wk transposes ---------------
__global__ __launch_bounds__(256)
void weights_prep(const float* __restrict__ Wq, const float* __restrict__ Wk,
                  const float* __restrict__ Wv,
                  _Float16* __restrict__ WqT, _Float16* __restrict__ WkT,
                  _Float16* __restrict__ wvh)
{
    __shared__ float t[64][65];
    const int p = blockIdx.x;
    const int tid = threadIdx.x;

    if (p < 288) {
        const long long i = ((long long)p * 256 + tid) * 8;
        const float4 a = *(const float4*)&Wv[i];
        const float4 b = *(const float4*)&Wv[i + 4];
        f16x8 o;
        o[0] = (_Float16)a.x; o[1] = (_Float16)a.y;
        o[2] = (_Float16)a.z; o[3] = (_Float16)a.w;
        o[4] = (_Float16)b.x; o[5] = (_Float16)b.y;
        o[6] = (_Float16)b.z; o[7] = (_Float16)b.w;
        *(f16x8*)&wvh[i] = o;
        return;
    }
    const int tno = p < 432 ? p - 288 : p - 432;
    const float* src = p < 432 ? Wq : Wk;
    _Float16* dst    = p < 432 ? WqT : WkT;
    const int r0 = (tno / 12) * 64, c0 = (tno % 12) * 64;
    const int tx = tid & 63, ty = tid >> 6;
    #pragma unroll
    for (int r = 0; r < 16; ++r) {
        const int row = ty * 16 + r;
        t[row][tx] = src[(size_t)(r0 + row) * 768 + c0 + tx];
    }
    __syncthreads();
    #pragma unroll
    for (int r = 0; r < 16; ++r) {
        const int orow = ty * 16 + r;
        dst[(size_t)(c0 + orow) * 768 + r0 + tx] = (_Float16)t[tx][orow];
    }
}

// colvec[d] = sum_e WkT[d][e]*bq[e]
__global__ __launch_bounds__(256)
void colvec_kernel(const _Float16* __restrict__ WkT, const float* __restrict__ bq,
                   float* __restrict__ colvec, int n)
{
    const int wv = threadIdx.x >> 6, lane = threadIdx.x & 63;
    const int d = blockIdx.x * 4 + wv;
    float s = 0.f;
    for (int e = lane; e < n; e += 64)
        s += (float)WkT[(size_t)d * n + e] * bq[e];
    #pragma unroll
    for (int off = 32; off; off >>= 1) s += __shfl_down(s, off, 64);
    if (lane == 0) colvec[d] = s;
}

// Unified row-pattern convert (one wave per 768-elem row); nontemporal reads
// (single-use fp32 streams; native ext_vector type for the builtin).
//  [0,4096)      k -> kh + cterm[row] = dot(k[row], colvec)
//  [4096,8192)   q -> qh
//  [8192,12288)  v -> vh
__global__ __launch_bounds__(256)
void row_prep(const float* __restrict__ k, const float* __restrict__ q,
              const float* __restrict__ v, const float* __restrict__ colvec,
              float* __restrict__ cterm, _Float16* __restrict__ kh,
              _Float16* __restrict__ qh, _Float16* __restrict__ vh)
{
    const int p = blockIdx.x;
    const int wv = threadIdx.x >> 6, lane = threadIdx.x & 63;

    if (p < 4096) {
        const long long row = (long long)p * 4 + wv;
        const float* kp = k + row * 768;
        _Float16* op = kh + row * 768;
        float s = 0.f;
        #pragma unroll
        for (int i = 0; i < 3; ++i) {
            const f32x4 a = __builtin_nontemporal_load(
                (const f32x4*)&kp[lane * 4 + i * 256]);
            const float4 c = *(const float4*)&colvec[lane * 4 + i * 256];
            s += a.x * c.x + a.y * c.y + a.z * c.z + a.w * c.w;
            f16x4 o;
            o[0] = (_Float16)a.x; o[1] = (_Float16)a.y;
            o[2] = (_Float16)a.z; o[3] = (_Float16)a.w;
            *(f16x4*)&op[lane * 4 + i * 256] = o;
        }
        #pragma unroll
        for (int off = 32; off; off >>= 1) s += __shfl_down(s, off, 64);
        if (lane == 0) cterm[row] = s;
        return;
    }
    const int pp = p & 4095;
    const float* src = p < 8192 ? q : v;
    _Float16* dst    = p < 8192 ? qh : vh;
    const long long row = (long long)pp * 4 + wv;
    const float* sp = src + row * 768;
    _Float16* op = dst + row * 768;
    #pragma unroll
    for (int i = 0; i < 3; ++i) {
        const f32x4 a = __builtin_nontemporal_load(
            (const f32x4*)&sp[lane * 4 + i * 256]);
        f16x4 o;
        o[0] = (_Float16)a.x; o[1] = (_Float16)a.y;
        o[2] = (_Float16)a.z; o[3] = (_Float16)a.w;
        *(f16x4*)&op[lane * 4 + i * 256] = o;
    }
}

// Pure row softmax (mask/cterm/temp already applied by the scores epilogue).
// One wave per row, no LDS, no barriers; fp32 scores -> compact fp16 P.
// Block p -> XCD p%8 handles rows [xcd*2048 + (p>>3)*4 .. +4) = same region
// the scores GEMM chunk map wrote on that XCD.
__global__ __launch_bounds__(256)
void softmax_rows(const float* __restrict__ P, _Float16* __restrict__ Pout)
{
    const int p = blockIdx.x;                       // 4096 blocks
    const int wv = threadIdx.x >> 6, lane = threadIdx.x & 63;
    const int row = (p & 7) * 2048 + (p >> 3) * 4 + wv;
    const float* rp = P + (long long)row * 1024;

    float vals[16];
    #pragma unroll
    for (int i = 0; i < 4; ++i) {
        const float4 a = *(const float4*)&rp[lane * 4 + i * 256];
        vals[i * 4 + 0] = a.x; vals[i * 4 + 1] = a.y;
        vals[i * 4 + 2] = a.z; vals[i * 4 + 3] = a.w;
    }

    float m = vals[0];
    #pragma unroll
    for (int j = 1; j < 16; ++j) m = fmaxf(m, vals[j]);
    #pragma unroll
    for (int off = 32; off; off >>= 1)
        m = fmaxf(m, __shfl_xor(m, off, 64));

    float e[16], s = 0.f;
    #pragma unroll
    for (int j = 0; j < 16; ++j) { e[j] = expf(vals[j] - m); s += e[j]; }
    #pragma unroll
    for (int off = 32; off; off >>= 1)
        s += __shfl_xor(s, off, 64);

    const float inv = 1.0f / s;
    _Float16* op = Pout + (long long)row * 1024;
    #pragma unroll
    for (int i = 0; i < 4; ++i) {
        f16x4 o;
        o[0] = (_Float16)(e[i * 4 + 0] * inv);
        o[1] = (_Float16)(e[i * 4 + 1] * inv);
        o[2] = (_Float16)(e[i * 4 + 2] * inv);
        o[3] = (_Float16)(e[i * 4 + 3] * inv);
        *(f16x4*)&op[lane * 4 + i * 256] = o;
    }
}

extern "C" void kernel_launch(void* const* d_in, const int* in_sizes, int n_in,
                              void* d_out, int out_size, void* d_ws, size_t ws_size,
                              hipStream_t stream)
{
    const float* q    = (const float*)d_in[0];
    const float* k    = (const float*)d_in[1];
    const float* v    = (const float*)d_in[2];
    const float* Wq   = (const float*)d_in[3];
    const float* bq   = (const float*)d_in[4];
    const float* Wk   = (const float*)d_in[5];
    const float* bk   = (const float*)d_in[6];   // row-constant -> cancels in softmax
    const float* Wv   = (const float*)d_in[7];
    const float* bv   = (const float*)d_in[8];
    const float* temp = (const float*)d_in[9];
    (void)bk;

    const int S = 1024, D = 768;

    // ws layout (bytes), end 197,725,184 (< proven 202,574,848).
    // P (32 MB compact fp16) overlays qh+kh, both dead by softmax time.
    char* ws = (char*)d_ws;
    _Float16* qh  = (_Float16*)(ws + 0);          // 24 MB (dead after scores)
    _Float16* kh  = (_Float16*)(ws + 25165824);   // 24 MB (dead after KG)
    _Float16* Pc  = (_Float16*)(ws + 0);          // 32 MB compact P
    _Float16* vh  = (_Float16*)(ws + 50331648);   // 24 MB
    _Float16* VT  = (_Float16*)(ws + 75497472);   // 24 MB
    _Float16* KG  = (_Float16*)(ws + 100663296);  // 24 MB
    float*  scores = (float*)(ws + 125829120);    // 64 MiB
    _Float16* wvh = (_Float16*)(ws + 192937984);  // 1.125 MB
    _Float16* WqT = (_Float16*)(ws + 194117632);
    _Float16* WkT = (_Float16*)(ws + 195297280);
    _Float16* G   = (_Float16*)(ws + 196476928);
    float* colvec = (float*)(ws + 197656576);
    float* cterm  = (float*)(ws + 197659648);

    dim3 blk(256);
    dim3 blk512(512);

    // weight preps, then colvec (needs WkT), then unified k/q/v row convert
    weights_prep<<<576, blk, 0, stream>>>(Wq, Wk, Wv, WqT, WkT, wvh);
    colvec_kernel<<<192, blk, 0, stream>>>(WkT, bq, colvec, D);
    row_prep<<<12288, blk, 0, stream>>>(k, q, v, colvec, cterm, kh, qh, vh);

    // G[d,d'] = sum_e Wq[e,d] Wk[e,d']  (tiny, 128^2 path)
    mfma_gemm<1, 0><<<dim3(6, 6, 1), blk, 0, stream>>>(
        WqT, WkT, nullptr, G,
        768, 768, 768, 768, 0, 0, 0);

    // KG[j,d] = sum_d' k[j,d'] G[d,d']  (M=16384 flat, N=768, K=768)
    mfma_gemm256<1, 0><<<dim3(3, 64, 1), blk512, 0, stream>>>(
        kh, G, nullptr, KG,
        768, 768, 768, 768, 0, 0, 0, nullptr, nullptr);

    // VT[b][e][s] = sum_d Wv[e,d] v[b,s,d] + bv[e]  (M=768, N=1024, K=768)
    mfma_gemm256<1, 2><<<dim3(4, 3, 16), blk512, 0, stream>>>(
        wvh, vh, bv, VT,
        768, 768, 768, 1024, 0, (long long)S * D, (long long)D * S,
        nullptr, nullptr);

    // scores[b] = (q[b] (KG[b])^T + cterm)/temp, diag -> -inf  (EPI=2)
    mfma_gemm256<2, 0><<<dim3(4, 4, 16), blk512, 0, stream>>>(
        qh, KG, nullptr, scores,
        768, 768, 768, 1024,
        (long long)S * D, (long long)S * D, (long long)S * S,
        temp, cterm);

    // pure row softmax -> compact fp16 P (stride 1024)
    softmax_rows<<<4096, blk, 0, stream>>>(scores, Pc);

    // out[b] = P[b] VT[b]^T  (M=1024, N=768, K=1024; compact P, lda=1024)
    mfma_gemm256<0, 0><<<dim3(3, 4, 16), blk512, 0, stream>>>(
        Pc, VT, nullptr, d_out,
        1024, 1024, 1024, 768,
        (long long)S * S, (long long)D * S, (long long)S * D,
        nullptr, nullptr);
}